// Round 17
// baseline (168.584 us; speedup 1.0000x reference)
//
#include <hip/hip_runtime.h>
#include <math.h>

#define IMG 401
#define NKP 17
#define NMID 32
#define CCH 150   // coarse channels: 0-16 kp(sig) | 17-50 so | 51-114 mo | 115-148 lo | 149 ss(sig)

// output region element offsets (f32 elements)
#define OFF_KP   0ULL
#define OFF_SO   5467234ULL
#define OFF_MID  16401702ULL
#define OFF_LONG 36984230ULL
#define OFF_SS   47918698ULL

#define SCc (13.0f/401.0f)
#define C0c (13.0f/802.0f - 0.5f)
#define ROWS 8             // tile = 32 x ROWS pixels
#define PSTR 120           // padded plane row stride bytes (15 cells * 8B)
#define PPL  225           // padded plane float2 count (15x15)

typedef float v2f __attribute__((ext_vector_type(2)));

__device__ float  g_coarse[2 * 169 * CCH];
__device__ float2 g_pairs[2 * 66 * 169];   // [n][66 fields][169]; 0-16 so, 17-48 mo, 49-65 lo

__constant__ int TO_KP_C[32] = {1,3,2,4,5,7,9,11,13,15,6,8,10,12,14,16,
                                0,1,0,2,0,5,7,5,11,13,0,6,8,6,12,14};

__device__ __forceinline__ float med3(float a, float b, float c) {
  return __builtin_amdgcn_fmed3f(a, b, c);
}
__device__ __forceinline__ void store2(float* p, float a, float b) {
  *reinterpret_cast<float2*>(p) = make_float2(a, b);
}
__device__ __forceinline__ v2f ldb(const float2* p, int byteoff) {
  return *reinterpret_cast<const v2f*>(reinterpret_cast<const char*>(p) + byteoff);
}

// ---------------- kernel 1: heads GEMM (proven round-13/16 structure) ----------------------
__global__ __launch_bounds__(512)
void heads_kernel(const float* __restrict__ x,
                  const float* __restrict__ kp_w, const float* __restrict__ kp_b,
                  const float* __restrict__ so_w, const float* __restrict__ so_b,
                  const float* __restrict__ mo_w, const float* __restrict__ mo_b,
                  const float* __restrict__ lo_w, const float* __restrict__ lo_b,
                  const float* __restrict__ ss_w, const float* __restrict__ ss_b) {
  __shared__ float xs[2][2048];
  __shared__ float ps[2][300];
  const int p0 = blockIdx.x * 2;
  const int tid = threadIdx.x;
  const float* xr = x + (size_t)p0 * 2048;
  for (int t = tid; t < 4096; t += 512) xs[t >> 11][t & 2047] = xr[t];
  __syncthreads();
  const int part = tid / 150;
  const int c = tid - part * 150;
  float a0 = 0.f, a1 = 0.f;
  const float* bptr = nullptr; int cc = 0; bool sig = false;
  if (part < 3) {
    const float* wptr; int Ch;
    if (c < 17)       { wptr = kp_w; bptr = kp_b; Ch = 17; cc = c;       sig = true; }
    else if (c < 51)  { wptr = so_w; bptr = so_b; Ch = 34; cc = c - 17; }
    else if (c < 115) { wptr = mo_w; bptr = mo_b; Ch = 64; cc = c - 51; }
    else if (c < 149) { wptr = lo_w; bptr = lo_b; Ch = 34; cc = c - 115; }
    else              { wptr = ss_w; bptr = ss_b; Ch = 1;  cc = 0;       sig = true; }
    const float* wp = wptr + cc;
    const int k0 = part * 683, k1 = (part == 2) ? 2048 : (k0 + 683);
    #pragma unroll 8
    for (int k = k0; k < k1; ++k) {
      float wv = wp[k * Ch];
      a0 = fmaf(xs[0][k], wv, a0);
      a1 = fmaf(xs[1][k], wv, a1);
    }
    if (part) { ps[0][c + (part - 1) * 150] = a0; ps[1][c + (part - 1) * 150] = a1; }
  }
  __syncthreads();
  if (part == 0) {
    float b = bptr[cc];
    float v0 = a0 + ps[0][c] + ps[0][c + 150] + b;
    float v1 = a1 + ps[1][c] + ps[1][c + 150] + b;
    if (sig) { v0 = 1.0f / (1.0f + expf(-v0)); v1 = 1.0f / (1.0f + expf(-v1)); }
    g_coarse[(size_t)p0 * CCH + c] = v0;
    g_coarse[(size_t)(p0 + 1) * CCH + c] = v1;
    if (c >= 17 && c < 149) {
      int rel = c - 17;
      int fi = rel >> 1, lo = rel & 1;
      int nn0 = p0 / 169, pp0 = p0 - nn0 * 169;
      int nn1 = (p0 + 1) / 169, pp1 = (p0 + 1) - nn1 * 169;
      ((float*)g_pairs)[(((size_t)nn0 * 66 + fi) * 169 + pp0) * 2 + lo] = v0;
      ((float*)g_pairs)[(((size_t)nn1 * 66 + fi) * 169 + pp1) * 2 + lo] = v1;
    }
  }
}

// ---------------- per-pixel context --------------------------------------------------------
struct Pix {
  v2f Q0, Q1, SWH, LOV, HIV;
  int obp;       // padded-plane byte offset of cell (cy,cx)'s 2x2 base
  int cell;      // 13x13 cell index (for g_coarse / unpadded gmo)
  int pix;
  bool valid;
};

__device__ __forceinline__ Pix mkpix(int n, int w, int h) {
  Pix P;
  P.valid = (w < IMG) && (h < IMG);
  v2f WH = {(float)w, (float)h};
  v2f S = WH * SCc + C0c;
  float cx = med3(floorf(S.x), 0.f, 11.f);
  float cy = med3(floorf(S.y), 0.f, 11.f);
  float fx = med3(S.x - cx, 0.f, 1.f);
  float fy = med3(S.y - cy, 0.f, 1.f);
  float gx = 1.f - fx, gy = 1.f - fy;
  P.Q0 = (v2f){gx, fx} * gy;
  P.Q1 = (v2f){gx, fx} * fy;
  P.obp  = (int)fmaf(cy, (float)PSTR, cx * 8.f) + (PSTR + 8);
  P.cell = (int)fmaf(cy, 13.f, cx);
  P.SWH = S;
  P.LOV = -WH;
  P.HIV = 400.f - WH;
  P.pix = (n * IMG + h) * IMG + w;
  return P;
}

// bilerp on padded LDS plane
__device__ __forceinline__ v2f blp4bP(const float2* __restrict__ F, const Pix& P) {
  return P.Q0.x * ldb(F, P.obp)            + P.Q0.y * ldb(F, P.obp + 8)
       + P.Q1.x * ldb(F, P.obp + PSTR)     + P.Q1.y * ldb(F, P.obp + PSTR + 8);
}
// bilerp on unpadded 13x13 global plane (mid bases)
__device__ __forceinline__ v2f blp4bG(const float2* __restrict__ F, const Pix& P) {
  int a = P.cell * 8;
  return P.Q0.x * ldb(F, a)       + P.Q0.y * ldb(F, a + 8)
       + P.Q1.x * ldb(F, a + 104) + P.Q1.y * ldb(F, a + 112);
}

// ----- 3x3-footprint sampler on replicated-pad plane: no clamps, incremental cell-crossing --
__device__ __forceinline__ v2f samplePk(const float2* __restrict__ F, v2f v, const Pix& P) {
  v2f F0 = {floorf(v.x), floorf(v.y)};
  v2f D  = v - F0;
  v2f E  = {D.x > 0.f ? 1.f : 0.f, D.y > 0.f ? 1.f : 0.f};
  v2f J1 = F0 + E;
  float sel = (F0.x < P.LOV.x || F0.y < P.LOV.y ||
               J1.x > P.HIV.x || J1.y > P.HIV.y) ? 0.f : 1.f;
  v2f S0 = F0 * SCc + P.SWH;                 // in [-0.49, 12.49]
  v2f C0 = {floorf(S0.x), floorf(S0.y)};     // in [-1, 12]: valid on padded plane
  v2f U0 = S0 - C0;
  v2f T  = E * SCc + U0;
  v2f DD = {T.x >= 1.f ? 1.f : 0.f, T.y >= 1.f ? 1.f : 0.f};  // cell crossing, exact {0,1}
  v2f U1 = T - DD;
  v2f G  = 1.f - D;
  v2f E0 = G * U0;
  v2f E1 = D * U1;
  v2f Fd = D - E1;
  v2f M  = Fd - Fd * DD;
  v2f W0 = (G - E0) + M;
  v2f Tt = Fd - E1;
  v2f W1 = (E0 + E1) + Tt * DD;
  v2f W2 = E1 * DD;
  int a = (int)fmaf(C0.y, (float)PSTR, C0.x * 8.f) + (PSTR + 8);
  v2f r0 = W0.x*ldb(F,a)          + W1.x*ldb(F,a+8)        + W2.x*ldb(F,a+16);
  v2f r1 = W0.x*ldb(F,a+PSTR)     + W1.x*ldb(F,a+PSTR+8)   + W2.x*ldb(F,a+PSTR+16);
  v2f r2 = W0.x*ldb(F,a+2*PSTR)   + W1.x*ldb(F,a+2*PSTR+8) + W2.x*ldb(F,a+2*PSTR+16);
  return (W0.y*r0 + W1.y*r1 + W2.y*r2) * sel;
}

// ---------------- kernel 2: padded planes in LDS, tile 32x8 --------------------------------
__global__ __launch_bounds__(512, 6)
void refine512_kernel(float* __restrict__ out) {
  __shared__ float2 Pf[34 * PPL + 16];  // planes 0-16: S fields; 17-33: L fields; +16 zero pad
  const int n = blockIdx.z;
  const int tid = threadIdx.x;
  const int w0 = blockIdx.x * 32, h0 = blockIdx.y * ROWS;

  {
    const float2* gS = g_pairs + (size_t)n * 66 * 169;          // fields 0-16
    const float2* gL = g_pairs + ((size_t)n * 66 + 49) * 169;   // fields 49-65
    for (int t = tid; t < 34 * PPL; t += 512) {
      int pl = t / PPL, idx = t - pl * PPL;
      int row = idx / 15, col = idx - row * 15;
      int sr = min(max(row - 1, 0), 12), sc = min(max(col - 1, 0), 12);
      const float2* src = (pl < 17) ? (gS + pl * 169) : (gL + (pl - 17) * 169);
      Pf[t] = src[sr * 13 + sc];
    }
    if (tid < 16) Pf[34 * PPL + tid] = make_float2(0.f, 0.f);
  }
  __syncthreads();

  const float* cb = g_coarse + (size_t)n * 169 * CCH;

  // ---- kp: ROWS*32*17 = 4352 elements ----
  #pragma unroll 1
  for (int it = 0; it < 9; ++it) {
    int f = it * 512 + tid;
    if (f >= ROWS * 544) break;
    int r = f / 544, rem = f - r * 544;
    int px = rem / 17, c = rem - px * 17;
    Pix P = mkpix(n, w0 + px, h0 + r);
    if (P.valid) {
      const float* b0 = cb + P.cell * CCH + c;
      out[OFF_KP + (size_t)P.pix * 17 + c] =
          P.Q0.x*b0[0] + P.Q0.y*b0[CCH] + P.Q1.x*b0[13*CCH] + P.Q1.y*b0[14*CCH];
    }
  }

  // ---- ss: ROWS*32 = 256 elements ----
  if (tid < ROWS * 32) {
    int r = tid >> 5, px = tid & 31;
    Pix P = mkpix(n, w0 + px, h0 + r);
    if (P.valid) {
      const float* b0 = cb + P.cell * CCH + 149;
      out[OFF_SS + (size_t)P.pix] =
          P.Q0.x*b0[0] + P.Q0.y*b0[CCH] + P.Q1.x*b0[13*CCH] + P.Q1.y*b0[14*CCH];
    }
  }

  // ---- so + long: ROWS*32*17 = 4352 pairs ----
  #pragma unroll 1
  for (int it = 0; it < 9; ++it) {
    int f = it * 512 + tid;
    if (f >= ROWS * 544) break;
    int r = f / 544, rem = f - r * 544;
    int px = rem / 17, k = rem - px * 17;
    Pix P = mkpix(n, w0 + px, h0 + r);
    const float2* S = Pf + k * PPL;
    const float2* L = Pf + (17 + k) * PPL;
    v2f sv = blp4bP(S, P);
    v2f b  = blp4bP(L, P);
    b += samplePk(L, b, P);
    b += samplePk(L, b, P);
    b += samplePk(S, b, P);
    b += samplePk(S, b, P);
    if (P.valid) {
      store2(out + OFF_SO   + (size_t)P.pix * 34 + 2 * k, sv.x, sv.y);
      store2(out + OFF_LONG + (size_t)P.pix * 34 + 2 * k, b.x, b.y);
    }
  }

  // ---- mid: ROWS*32*32 = 8192 pairs ----
  const float2* gmo = g_pairs + ((size_t)n * 66 + 17) * 169;
  #pragma unroll 1
  for (int it = 0; it < 16; ++it) {
    int f = it * 512 + tid;
    int r = f >> 10, rem = f & 1023;
    int px = rem >> 5, g = rem & 31;
    Pix P = mkpix(n, w0 + px, h0 + r);
    v2f b = blp4bG(gmo + g * 169, P);
    const float2* S = Pf + TO_KP_C[g] * PPL;
    b += samplePk(S, b, P);
    b += samplePk(S, b, P);
    if (P.valid) store2(out + OFF_MID + (size_t)P.pix * 64 + 2 * g, b.x, b.y);
  }
}

extern "C" void kernel_launch(void* const* d_in, const int* in_sizes, int n_in,
                              void* d_out, int out_size, void* d_ws, size_t ws_size,
                              hipStream_t stream) {
  const float* x    = (const float*)d_in[0];
  const float* kp_w = (const float*)d_in[1];
  const float* kp_b = (const float*)d_in[2];
  const float* so_w = (const float*)d_in[3];
  const float* so_b = (const float*)d_in[4];
  const float* mo_w = (const float*)d_in[5];
  const float* mo_b = (const float*)d_in[6];
  const float* lo_w = (const float*)d_in[7];
  const float* lo_b = (const float*)d_in[8];
  const float* ss_w = (const float*)d_in[9];
  const float* ss_b = (const float*)d_in[10];
  float* out = (float*)d_out;

  heads_kernel<<<dim3(169), dim3(512), 0, stream>>>(x, kp_w, kp_b, so_w, so_b,
                                                    mo_w, mo_b, lo_w, lo_b,
                                                    ss_w, ss_b);
  refine512_kernel<<<dim3(13, 51, 2), dim3(512), 0, stream>>>(out);
}

// Round 18
// 160.797 us; speedup vs baseline: 1.0484x; 1.0484x over previous
//
#include <hip/hip_runtime.h>
#include <math.h>

#define IMG 401
#define NKP 17
#define NMID 32
#define CCH 150   // coarse channels: 0-16 kp(sig) | 17-50 so | 51-114 mo | 115-148 lo | 149 ss(sig)

// output region element offsets (f32 elements)
#define OFF_KP   0ULL
#define OFF_SO   5467234ULL
#define OFF_MID  16401702ULL
#define OFF_LONG 36984230ULL
#define OFF_SS   47918698ULL

#define SCc (13.0f/401.0f)
#define C0c (13.0f/802.0f - 0.5f)
#define ROWS 8             // tile = 32 x ROWS pixels
#define PSTR 120           // padded S-plane row stride bytes (15 cells * 8B)
#define PPL  225           // padded S-plane float2 count (15x15)
#define LBASE (17 * PPL)   // float2 index of first L plane in Pf

typedef float v2f __attribute__((ext_vector_type(2)));

__device__ float  g_coarse[2 * 169 * CCH];
__device__ float2 g_pairs[2 * 66 * 169];   // [n][66 fields][169]; 0-16 so, 17-48 mo, 49-65 lo

__constant__ int TO_KP_C[32] = {1,3,2,4,5,7,9,11,13,15,6,8,10,12,14,16,
                                0,1,0,2,0,5,7,5,11,13,0,6,8,6,12,14};

__device__ __forceinline__ float med3(float a, float b, float c) {
  return __builtin_amdgcn_fmed3f(a, b, c);
}
__device__ __forceinline__ void store2(float* p, float a, float b) {
  *reinterpret_cast<float2*>(p) = make_float2(a, b);
}
__device__ __forceinline__ v2f ldb(const float2* p, int byteoff) {
  return *reinterpret_cast<const v2f*>(reinterpret_cast<const char*>(p) + byteoff);
}

// ---------------- kernel 1: heads GEMM (proven round-13/16 structure) ----------------------
__global__ __launch_bounds__(512)
void heads_kernel(const float* __restrict__ x,
                  const float* __restrict__ kp_w, const float* __restrict__ kp_b,
                  const float* __restrict__ so_w, const float* __restrict__ so_b,
                  const float* __restrict__ mo_w, const float* __restrict__ mo_b,
                  const float* __restrict__ lo_w, const float* __restrict__ lo_b,
                  const float* __restrict__ ss_w, const float* __restrict__ ss_b) {
  __shared__ float xs[2][2048];
  __shared__ float ps[2][300];
  const int p0 = blockIdx.x * 2;
  const int tid = threadIdx.x;
  const float* xr = x + (size_t)p0 * 2048;
  for (int t = tid; t < 4096; t += 512) xs[t >> 11][t & 2047] = xr[t];
  __syncthreads();
  const int part = tid / 150;
  const int c = tid - part * 150;
  float a0 = 0.f, a1 = 0.f;
  const float* bptr = nullptr; int cc = 0; bool sig = false;
  if (part < 3) {
    const float* wptr; int Ch;
    if (c < 17)       { wptr = kp_w; bptr = kp_b; Ch = 17; cc = c;       sig = true; }
    else if (c < 51)  { wptr = so_w; bptr = so_b; Ch = 34; cc = c - 17; }
    else if (c < 115) { wptr = mo_w; bptr = mo_b; Ch = 64; cc = c - 51; }
    else if (c < 149) { wptr = lo_w; bptr = lo_b; Ch = 34; cc = c - 115; }
    else              { wptr = ss_w; bptr = ss_b; Ch = 1;  cc = 0;       sig = true; }
    const float* wp = wptr + cc;
    const int k0 = part * 683, k1 = (part == 2) ? 2048 : (k0 + 683);
    #pragma unroll 8
    for (int k = k0; k < k1; ++k) {
      float wv = wp[k * Ch];
      a0 = fmaf(xs[0][k], wv, a0);
      a1 = fmaf(xs[1][k], wv, a1);
    }
    if (part) { ps[0][c + (part - 1) * 150] = a0; ps[1][c + (part - 1) * 150] = a1; }
  }
  __syncthreads();
  if (part == 0) {
    float b = bptr[cc];
    float v0 = a0 + ps[0][c] + ps[0][c + 150] + b;
    float v1 = a1 + ps[1][c] + ps[1][c + 150] + b;
    if (sig) { v0 = 1.0f / (1.0f + expf(-v0)); v1 = 1.0f / (1.0f + expf(-v1)); }
    g_coarse[(size_t)p0 * CCH + c] = v0;
    g_coarse[(size_t)(p0 + 1) * CCH + c] = v1;
    if (c >= 17 && c < 149) {
      int rel = c - 17;
      int fi = rel >> 1, lo = rel & 1;
      int nn0 = p0 / 169, pp0 = p0 - nn0 * 169;
      int nn1 = (p0 + 1) / 169, pp1 = (p0 + 1) - nn1 * 169;
      ((float*)g_pairs)[(((size_t)nn0 * 66 + fi) * 169 + pp0) * 2 + lo] = v0;
      ((float*)g_pairs)[(((size_t)nn1 * 66 + fi) * 169 + pp1) * 2 + lo] = v1;
    }
  }
}

// ---------------- per-pixel context --------------------------------------------------------
struct Pix {
  v2f Q0, Q1, SWH, LOV, HIV;
  int ob;        // unpadded 13x13 plane byte offset of cell (cy,cx)
  int obp;       // padded 15x15 plane byte offset of cell's 2x2 base
  int pix;
  bool valid;
};

__device__ __forceinline__ Pix mkpix(int n, int w, int h) {
  Pix P;
  P.valid = (w < IMG) && (h < IMG);
  v2f WH = {(float)w, (float)h};
  v2f S = WH * SCc + C0c;
  float cx = med3(floorf(S.x), 0.f, 11.f);
  float cy = med3(floorf(S.y), 0.f, 11.f);
  float fx = med3(S.x - cx, 0.f, 1.f);
  float fy = med3(S.y - cy, 0.f, 1.f);
  float gx = 1.f - fx, gy = 1.f - fy;
  P.Q0 = (v2f){gx, fx} * gy;
  P.Q1 = (v2f){gx, fx} * fy;
  P.ob  = (int)fmaf(cy, 104.f, cx * 8.f);
  P.obp = (int)fmaf(cy, (float)PSTR, cx * 8.f) + (PSTR + 8);
  P.SWH = S;
  P.LOV = -WH;
  P.HIV = 400.f - WH;
  P.pix = (n * IMG + h) * IMG + w;
  return P;
}

// bilerp on unpadded 13x13 plane (LDS L, or global mo)
__device__ __forceinline__ v2f blp4bU(const float2* __restrict__ F, const Pix& P) {
  return P.Q0.x * ldb(F, P.ob)       + P.Q0.y * ldb(F, P.ob + 8)
       + P.Q1.x * ldb(F, P.ob + 104) + P.Q1.y * ldb(F, P.ob + 112);
}
// bilerp on padded 15x15 LDS plane (S)
__device__ __forceinline__ v2f blp4bP(const float2* __restrict__ F, const Pix& P) {
  return P.Q0.x * ldb(F, P.obp)        + P.Q0.y * ldb(F, P.obp + 8)
       + P.Q1.x * ldb(F, P.obp + PSTR) + P.Q1.y * ldb(F, P.obp + PSTR + 8);
}

// ----- sampler on unpadded 13x13 plane (round-16 proven, med3 clamps) ----------------------
__device__ __forceinline__ v2f sampleU16(const float2* __restrict__ F, v2f v, const Pix& P) {
  v2f F0 = {floorf(v.x), floorf(v.y)};
  v2f D  = v - F0;
  v2f E  = {D.x > 0.f ? 1.f : 0.f, D.y > 0.f ? 1.f : 0.f};
  v2f J1 = F0 + E;
  float sel = (F0.x < P.LOV.x || F0.y < P.LOV.y ||
               J1.x > P.HIV.x || J1.y > P.HIV.y) ? 0.f : 1.f;
  v2f S0 = F0 * SCc + P.SWH;
  v2f S1 = E  * SCc + S0;
  v2f C0 = {med3(floorf(S0.x), 0.f, 11.f), med3(floorf(S0.y), 0.f, 11.f)};
  v2f C1 = {med3(floorf(S1.x), 0.f, 11.f), med3(floorf(S1.y), 0.f, 11.f)};
  v2f U0t = S0 - C0;
  v2f U0 = {med3(U0t.x, 0.f, 1.f), med3(U0t.y, 0.f, 1.f)};
  v2f U1t = S1 - C1;
  v2f U1 = {med3(U1t.x, 0.f, 1.f), med3(U1t.y, 0.f, 1.f)};
  v2f DD = C1 - C0;
  v2f G  = 1.f - D;
  v2f E0 = G * U0;
  v2f E1 = D * U1;
  v2f Fd = D - E1;
  v2f M  = Fd - Fd * DD;
  v2f W0 = (G - E0) + M;
  v2f Tt = Fd - E1;
  v2f W1 = (E0 + E1) + Tt * DD;
  v2f W2 = E1 * DD;
  int a = (int)fmaf(C0.y, 104.f, C0.x * 8.f);
  v2f r0 = W0.x*ldb(F,a)     + W1.x*ldb(F,a+8)   + W2.x*ldb(F,a+16);
  v2f r1 = W0.x*ldb(F,a+104) + W1.x*ldb(F,a+112) + W2.x*ldb(F,a+120);
  v2f r2 = W0.x*ldb(F,a+208) + W1.x*ldb(F,a+216) + W2.x*ldb(F,a+224);
  return (W0.y*r0 + W1.y*r1 + W2.y*r2) * sel;
}

// ----- sampler on padded 15x15 plane (round-17 proven: no clamps, incremental crossing) ----
__device__ __forceinline__ v2f samplePad(const float2* __restrict__ F, v2f v, const Pix& P) {
  v2f F0 = {floorf(v.x), floorf(v.y)};
  v2f D  = v - F0;
  v2f E  = {D.x > 0.f ? 1.f : 0.f, D.y > 0.f ? 1.f : 0.f};
  v2f J1 = F0 + E;
  float sel = (F0.x < P.LOV.x || F0.y < P.LOV.y ||
               J1.x > P.HIV.x || J1.y > P.HIV.y) ? 0.f : 1.f;
  v2f S0 = F0 * SCc + P.SWH;                 // in [-0.49, 12.49]
  v2f C0 = {floorf(S0.x), floorf(S0.y)};     // in [-1, 12]: valid on padded plane
  v2f U0 = S0 - C0;
  v2f T  = E * SCc + U0;
  v2f DD = {T.x >= 1.f ? 1.f : 0.f, T.y >= 1.f ? 1.f : 0.f};  // cell crossing, exact {0,1}
  v2f U1 = T - DD;
  v2f G  = 1.f - D;
  v2f E0 = G * U0;
  v2f E1 = D * U1;
  v2f Fd = D - E1;
  v2f M  = Fd - Fd * DD;
  v2f W0 = (G - E0) + M;
  v2f Tt = Fd - E1;
  v2f W1 = (E0 + E1) + Tt * DD;
  v2f W2 = E1 * DD;
  int a = (int)fmaf(C0.y, (float)PSTR, C0.x * 8.f) + (PSTR + 8);
  v2f r0 = W0.x*ldb(F,a)        + W1.x*ldb(F,a+8)        + W2.x*ldb(F,a+16);
  v2f r1 = W0.x*ldb(F,a+PSTR)   + W1.x*ldb(F,a+PSTR+8)   + W2.x*ldb(F,a+PSTR+16);
  v2f r2 = W0.x*ldb(F,a+2*PSTR) + W1.x*ldb(F,a+2*PSTR+8) + W2.x*ldb(F,a+2*PSTR+16);
  return (W0.y*r0 + W1.y*r1 + W2.y*r2) * sel;
}

// ---------------- kernel 2: S padded + L unpadded in LDS, tile 32x8 ------------------------
__global__ __launch_bounds__(512, 6)
void refine512_kernel(float* __restrict__ out) {
  // S planes 0-16 padded 15x15; L planes 0-16 unpadded 13x13; +16 zero tail pad
  __shared__ float2 Pf[LBASE + 17 * 169 + 16];
  const int n = blockIdx.z;
  const int tid = threadIdx.x;
  const int w0 = blockIdx.x * 32, h0 = blockIdx.y * ROWS;

  {
    const float2* gS = g_pairs + (size_t)n * 66 * 169;          // fields 0-16 (so)
    const float2* gL = g_pairs + ((size_t)n * 66 + 49) * 169;   // fields 49-65 (lo)
    for (int t = tid; t < 17 * PPL; t += 512) {
      int pl = t / PPL, idx = t - pl * PPL;
      int row = idx / 15, col = idx - row * 15;
      int sr = min(max(row - 1, 0), 12), sc = min(max(col - 1, 0), 12);
      Pf[t] = gS[pl * 169 + sr * 13 + sc];
    }
    for (int t = tid; t < 17 * 169; t += 512) Pf[LBASE + t] = gL[t];
    if (tid < 16) Pf[LBASE + 17 * 169 + tid] = make_float2(0.f, 0.f);
  }
  __syncthreads();

  const float* cb = g_coarse + (size_t)n * 169 * CCH;

  // ---- kp: ROWS*32*17 = 4352 elements ----
  #pragma unroll 1
  for (int it = 0; it < 9; ++it) {
    int f = it * 512 + tid;
    if (f >= ROWS * 544) break;
    int r = f / 544, rem = f - r * 544;
    int px = rem / 17, c = rem - px * 17;
    Pix P = mkpix(n, w0 + px, h0 + r);
    if (P.valid) {
      const float* b0 = cb + (P.ob >> 3) * CCH + c;
      out[OFF_KP + (size_t)P.pix * 17 + c] =
          P.Q0.x*b0[0] + P.Q0.y*b0[CCH] + P.Q1.x*b0[13*CCH] + P.Q1.y*b0[14*CCH];
    }
  }

  // ---- ss: ROWS*32 = 256 elements ----
  if (tid < ROWS * 32) {
    int r = tid >> 5, px = tid & 31;
    Pix P = mkpix(n, w0 + px, h0 + r);
    if (P.valid) {
      const float* b0 = cb + (P.ob >> 3) * CCH + 149;
      out[OFF_SS + (size_t)P.pix] =
          P.Q0.x*b0[0] + P.Q0.y*b0[CCH] + P.Q1.x*b0[13*CCH] + P.Q1.y*b0[14*CCH];
    }
  }

  // ---- so + long: ROWS*32*17 = 4352 pairs ----
  #pragma unroll 1
  for (int it = 0; it < 9; ++it) {
    int f = it * 512 + tid;
    if (f >= ROWS * 544) break;
    int r = f / 544, rem = f - r * 544;
    int px = rem / 17, k = rem - px * 17;
    Pix P = mkpix(n, w0 + px, h0 + r);
    const float2* S = Pf + k * PPL;             // padded
    const float2* L = Pf + LBASE + k * 169;     // unpadded
    v2f sv = blp4bP(S, P);
    v2f b  = blp4bU(L, P);
    b += sampleU16(L, b, P);
    b += sampleU16(L, b, P);
    b += samplePad(S, b, P);
    b += samplePad(S, b, P);
    if (P.valid) {
      store2(out + OFF_SO   + (size_t)P.pix * 34 + 2 * k, sv.x, sv.y);
      store2(out + OFF_LONG + (size_t)P.pix * 34 + 2 * k, b.x, b.y);
    }
  }

  // ---- mid: ROWS*32*32 = 8192 pairs ----
  const float2* gmo = g_pairs + ((size_t)n * 66 + 17) * 169;
  #pragma unroll 1
  for (int it = 0; it < 16; ++it) {
    int f = it * 512 + tid;
    int r = f >> 10, rem = f & 1023;
    int px = rem >> 5, g = rem & 31;
    Pix P = mkpix(n, w0 + px, h0 + r);
    v2f b = blp4bU(gmo + g * 169, P);
    const float2* S = Pf + TO_KP_C[g] * PPL;    // padded
    b += samplePad(S, b, P);
    b += samplePad(S, b, P);
    if (P.valid) store2(out + OFF_MID + (size_t)P.pix * 64 + 2 * g, b.x, b.y);
  }
}

extern "C" void kernel_launch(void* const* d_in, const int* in_sizes, int n_in,
                              void* d_out, int out_size, void* d_ws, size_t ws_size,
                              hipStream_t stream) {
  const float* x    = (const float*)d_in[0];
  const float* kp_w = (const float*)d_in[1];
  const float* kp_b = (const float*)d_in[2];
  const float* so_w = (const float*)d_in[3];
  const float* so_b = (const float*)d_in[4];
  const float* mo_w = (const float*)d_in[5];
  const float* mo_b = (const float*)d_in[6];
  const float* lo_w = (const float*)d_in[7];
  const float* lo_b = (const float*)d_in[8];
  const float* ss_w = (const float*)d_in[9];
  const float* ss_b = (const float*)d_in[10];
  float* out = (float*)d_out;

  heads_kernel<<<dim3(169), dim3(512), 0, stream>>>(x, kp_w, kp_b, so_w, so_b,
                                                    mo_w, mo_b, lo_w, lo_b,
                                                    ss_w, ss_b);
  refine512_kernel<<<dim3(13, 51, 2), dim3(512), 0, stream>>>(out);
}